// Round 19
// baseline (216.431 us; speedup 1.0000x reference)
//
#include <hip/hip_runtime.h>

#define B_ 8
#define T_ 8192
#define D_ 1024
#define GD_ 64
#define WSZ_ 16
#define NWIN_ (T_ / WSZ_)   // 512
#define PL1_ (4 * 32 * 512) // W1F per-split-plane elems
#define PL2_ (4 * 2 * 512)  // W2F per-split-plane elems

typedef __attribute__((ext_vector_type(8))) short short8v;
typedef __attribute__((ext_vector_type(4))) float f32x4;

__device__ __forceinline__ unsigned bf16rne(unsigned u) {
  return (u + 0x7FFFu + ((u >> 16) & 1u)) >> 16;
}
// f32 -> 2 bf16 terms: x = h + m + O(2^-17 x)
__device__ __forceinline__ void split2(float x, short& h, short& m) {
  const unsigned uh = bf16rne(__float_as_uint(x));
  const float fh = __uint_as_float(uh << 16);
  const float r1 = x - fh;
  const unsigned um = bf16rne(__float_as_uint(r1));
  h = (short)uh; m = (short)um;
}

// ---------------------------------------------------------------------------
// K0: split W1/W2 into MFMA-fragment-tiled bf16 planes (2 splits).
// ---------------------------------------------------------------------------
__global__ __launch_bounds__(256) void k_prep(
    const float* __restrict__ W1, const float* __restrict__ W2,
    short* __restrict__ w1f, short* __restrict__ w2f)
{
  const int i = blockIdx.x * 256 + threadIdx.x;
  if (i < 4 * 32 * 64 * 8) {
    const int e = i & 7;
    const int lane = (i >> 3) & 63;
    const int tk = (i >> 9) & 31;
    const int tg = i >> 14;
    const int g = tg * 16 + (lane & 15);
    const int k = tk * 32 + ((lane >> 4) << 3) + e;
    short h, m;
    split2(W1[(long)k * GD_ + g], h, m);
    const int off = ((tg * 32 + tk) << 9) + lane * 8 + e;
    w1f[off] = h;
    w1f[PL1_ + off] = m;
  } else {
    const int j = i - 4 * 32 * 64 * 8;       // < 4096
    const int e = j & 7;
    const int lane = (j >> 3) & 63;
    const int tk = (j >> 9) & 1;
    const int tg = j >> 10;
    const int g = tg * 16 + (lane & 15);
    const int k = tk * 32 + ((lane >> 4) << 3) + e;
    short h, m;
    split2(W2[(long)k * GD_ + g], h, m);
    const int off = ((tg * 2 + tk) << 9) + lane * 8 + e;
    w2f[off] = h;
    w2f[PL2_ + off] = m;
  }
}

// ---------------------------------------------------------------------------
// K1 (fully fused): sims -> per-window greedy pick -> emit z_new/lens_new.
// R14 champion structure: 64 tok/block, 256 thr, K=64 chunks, double-
// buffered z split planes, MFMA 2-split (hh, hm, mh). When doEmit (budget
// uniform & always achievable: extra==0, base<=5), picks give exactly
// (16-base) kept rows/window -> static output offsets; pick+emit in-block.
// ---------------------------------------------------------------------------
__global__ __launch_bounds__(256) void k_fused(
    const float* __restrict__ z, const short* __restrict__ w1f,
    const short* __restrict__ w2f, const int* __restrict__ lensp,
    float* __restrict__ out, double* __restrict__ sims_out,
    int TL, int baseBudget, int doEmit)
{
  __shared__ short Zsp[2][3][64][72];  // dbuf z splits; H splits in [0]
  __shared__ double den[64];
  __shared__ double simsL[4][WSZ_ - 1];
  __shared__ int mrmL[4];
  float (*Gf)[72] = (float (*)[72]) & Zsp[0][0][0][0];

  const int tid = threadIdx.x;
  const int lane = tid & 63;
  const int w = tid >> 6;
  const int th = w & 1;
  const int gh = w >> 1;
  const int cl = lane & 15;
  const int ko8 = (lane >> 4) * 8;
  const long bt0 = (long)blockIdx.x * 64;

  const int r = tid >> 2;
  const int kq = tid & 3;
  const float* zbase = z + (bt0 + r) * D_ + kq * 16;

  f32x4 acc[2][2];
#pragma unroll
  for (int a = 0; a < 2; ++a)
#pragma unroll
    for (int b = 0; b < 2; ++b) acc[a][b] = (f32x4){0.f, 0.f, 0.f, 0.f};

  auto stage = [&](const float4 (&pz)[4], int buf) {
    short h[16], m[16];
#pragma unroll
    for (int q = 0; q < 4; ++q) {
      split2(pz[q].x, h[4 * q + 0], m[4 * q + 0]);
      split2(pz[q].y, h[4 * q + 1], m[4 * q + 1]);
      split2(pz[q].z, h[4 * q + 2], m[4 * q + 2]);
      split2(pz[q].w, h[4 * q + 3], m[4 * q + 3]);
    }
    const int co = kq * 16;
    *(short8v*)&Zsp[buf][0][r][co] =
        (short8v){h[0], h[1], h[2], h[3], h[4], h[5], h[6], h[7]};
    *(short8v*)&Zsp[buf][0][r][co + 8] =
        (short8v){h[8], h[9], h[10], h[11], h[12], h[13], h[14], h[15]};
    *(short8v*)&Zsp[buf][1][r][co] =
        (short8v){m[0], m[1], m[2], m[3], m[4], m[5], m[6], m[7]};
    *(short8v*)&Zsp[buf][1][r][co + 8] =
        (short8v){m[8], m[9], m[10], m[11], m[12], m[13], m[14], m[15]};
  };

  auto mfma_chunk = [&](int buf, int c) {
#pragma unroll
    for (int ks = 0; ks < 2; ++ks) {
      const int ko = ks * 32 + ko8;
      short8v af[2][2], bf[2][2];
#pragma unroll
      for (int a = 0; a < 2; ++a)
#pragma unroll
        for (int s = 0; s < 2; ++s)
          af[a][s] = *(const short8v*)(
              w1f + s * PL1_ +
              ((((gh * 2 + a) * 32) + (c * 2 + ks)) << 9) + lane * 8);
#pragma unroll
      for (int b = 0; b < 2; ++b)
#pragma unroll
        for (int s = 0; s < 2; ++s)
          bf[b][s] = *(const short8v*)&Zsp[buf][s][th * 32 + b * 16 + cl][ko];
#pragma unroll
      for (int a = 0; a < 2; ++a)
#pragma unroll
        for (int b = 0; b < 2; ++b) {
          f32x4 d = acc[a][b];
          d = __builtin_amdgcn_mfma_f32_16x16x32_bf16(af[a][0], bf[b][0], d, 0, 0, 0);
          d = __builtin_amdgcn_mfma_f32_16x16x32_bf16(af[a][0], bf[b][1], d, 0, 0, 0);
          d = __builtin_amdgcn_mfma_f32_16x16x32_bf16(af[a][1], bf[b][0], d, 0, 0, 0);
          acc[a][b] = d;
        }
    }
  };

  // ================= phase A: H = z @ W1, pipelined =======================
  float4 pzA[4], pzB[4];
#pragma unroll
  for (int q = 0; q < 4; ++q) pzA[q] = *(const float4*)(zbase + 4 * q);

#pragma unroll 1
  for (int c = 0; c < 16; c += 2) {
    if (c + 1 < 16) {
#pragma unroll
      for (int q = 0; q < 4; ++q)
        pzB[q] = *(const float4*)(zbase + (c + 1) * 64 + 4 * q);
    }
    stage(pzA, 0);
    __syncthreads();
    mfma_chunk(0, c);
    if (c + 2 < 16) {
#pragma unroll
      for (int q = 0; q < 4; ++q)
        pzA[q] = *(const float4*)(zbase + (c + 2) * 64 + 4 * q);
    }
    stage(pzB, 1);
    __syncthreads();
    mfma_chunk(1, c + 1);
  }
  __syncthreads();

  // ---- relu + H splits into Zsp[0] as [tok][gd]
#pragma unroll
  for (int a = 0; a < 2; ++a)
#pragma unroll
    for (int b = 0; b < 2; ++b) {
      const int t = th * 32 + b * 16 + cl;
      const int g0 = gh * 32 + a * 16 + (lane >> 4) * 4;
      short hh[4], hm[4];
#pragma unroll
      for (int e = 0; e < 4; ++e)
        split2(fmaxf(acc[a][b][e], 0.0f), hh[e], hm[e]);
      Zsp[0][0][t][g0 + 0] = hh[0]; Zsp[0][0][t][g0 + 1] = hh[1];
      Zsp[0][0][t][g0 + 2] = hh[2]; Zsp[0][0][t][g0 + 3] = hh[3];
      Zsp[0][1][t][g0 + 0] = hm[0]; Zsp[0][1][t][g0 + 1] = hm[1];
      Zsp[0][1][t][g0 + 2] = hm[2]; Zsp[0][1][t][g0 + 3] = hm[3];
    }
  __syncthreads();

  // ================= phase B: G = H @ W2 (K = 64) =========================
#pragma unroll
  for (int a = 0; a < 2; ++a)
#pragma unroll
    for (int b = 0; b < 2; ++b) acc[a][b] = (f32x4){0.f, 0.f, 0.f, 0.f};
#pragma unroll
  for (int ks = 0; ks < 2; ++ks) {
    const int ko = ks * 32 + ko8;
    short8v af[2][2], bf[2][2];
#pragma unroll
    for (int a = 0; a < 2; ++a)
#pragma unroll
      for (int s = 0; s < 2; ++s)
        af[a][s] = *(const short8v*)(
            w2f + s * PL2_ + ((((gh * 2 + a) * 2) + ks) << 9) + lane * 8);
#pragma unroll
    for (int b = 0; b < 2; ++b)
#pragma unroll
      for (int s = 0; s < 2; ++s)
        bf[b][s] = *(const short8v*)&Zsp[0][s][th * 32 + b * 16 + cl][ko];
#pragma unroll
    for (int a = 0; a < 2; ++a)
#pragma unroll
      for (int b = 0; b < 2; ++b) {
        f32x4 d = acc[a][b];
        d = __builtin_amdgcn_mfma_f32_16x16x32_bf16(af[a][0], bf[b][0], d, 0, 0, 0);
        d = __builtin_amdgcn_mfma_f32_16x16x32_bf16(af[a][0], bf[b][1], d, 0, 0, 0);
        d = __builtin_amdgcn_mfma_f32_16x16x32_bf16(af[a][1], bf[b][0], d, 0, 0, 0);
        acc[a][b] = d;
      }
  }
  __syncthreads();                   // all H-split reads done (overlay!)

  // ---- raw G (f32) -> overlay
#pragma unroll
  for (int a = 0; a < 2; ++a)
#pragma unroll
    for (int b = 0; b < 2; ++b) {
      const int t = th * 32 + b * 16 + cl;
      const int g0 = gh * 32 + a * 16 + (lane >> 4) * 4;
      *(f32x4*)&Gf[t][g0] = acc[a][b];
    }
  __syncthreads();

  // ---- norms (f64)
  if (tid < 64) {
    double ss = 0.0;
#pragma unroll
    for (int q = 0; q < 16; ++q) {
      const float4 v = *(const float4*)&Gf[tid][4 * q];
      ss += (double)v.x * v.x + (double)v.y * v.y +
            (double)v.z * v.z + (double)v.w * v.w;
    }
    den[tid] = sqrt(ss) + 1e-8;
  }
  __syncthreads();

  // ---- sims (f64) -> LDS (and global if fallback path)
  if (tid < 4 * (WSZ_ - 1)) {
    const int ww = tid / (WSZ_ - 1), e = tid % (WSZ_ - 1);
    const int t = ww * WSZ_ + e;
    double s = 0.0;
#pragma unroll
    for (int q = 0; q < 16; ++q) {
      const float4 x = *(const float4*)&Gf[t][4 * q];
      const float4 y = *(const float4*)&Gf[t + 1][4 * q];
      s += (double)x.x * y.x + (double)x.y * y.y +
           (double)x.z * y.z + (double)x.w * y.w;
    }
    const double sv = s / (den[t] * den[t + 1]);
    simsL[ww][e] = sv;
    if (!doEmit)
      sims_out[((long)blockIdx.x * 4 + ww) * (WSZ_ - 1) + e] = sv;
  }
  if (!doEmit) return;
  __syncthreads();

  // ---- per-window pick (exact greedy, budget = baseBudget)
  if (tid < 4) {
    double v[WSZ_ - 1];
    int id[WSZ_ - 1];
    for (int e = 0; e < WSZ_ - 1; ++e) { v[e] = simsL[tid][e]; id[e] = e; }
    for (int i = 1; i < WSZ_ - 1; ++i) {
      const double dv = v[i]; const int di = id[i];
      int j = i - 1;
      while (j >= 0 && v[j] < dv) { v[j + 1] = v[j]; id[j + 1] = id[j]; --j; }
      v[j + 1] = dv; id[j + 1] = di;
    }
    bool used[WSZ_];
    for (int i = 0; i < WSZ_; ++i) used[i] = false;
    int mrm = 0, picked = 0;
    for (int ii = 0; ii < WSZ_ - 1; ++ii) {
      const int e = id[ii];
      if (picked < baseBudget && !used[e] && !used[e + 1]) {
        used[e] = used[e + 1] = true;
        mrm |= (1 << (e + 1));
        ++picked;
      }
    }
    mrmL[tid] = mrm;
  }
  __syncthreads();

  // ---- emit: static offsets (keptW per window), coalesced float4 rows
  const int keptW = WSZ_ - baseBudget;
  const int bb = (int)(bt0 / T_);
  const int tb = (int)(bt0 % T_);
  const int wb = tb / WSZ_;
  const float* zbat = z + (long)bb * T_ * D_;
  const int* lbat = lensp + bb * T_;
  float* lout = out + (long)B_ * TL * D_;

#pragma unroll 1
  for (int ww2 = 0; ww2 < 4; ++ww2) {
    const int mrm = mrmL[ww2];
    int p = keptW * (wb + ww2);
    const int t0 = tb + ww2 * WSZ_;
#pragma unroll 1
    for (int i = 0; i < WSZ_; ++i) {
      if ((mrm >> i) & 1) continue;
      const int t = t0 + i;
      const bool ab = (i < WSZ_ - 1) && ((mrm >> (i + 1)) & 1);
      float4 o = *(const float4*)(zbat + (long)t * D_ + tid * 4);
      if (ab) {
        const float wi = (float)lbat[t], wj = (float)lbat[t + 1];
        const float s = wi + wj;
        const float4 zj = *(const float4*)(zbat + (long)(t + 1) * D_ + tid * 4);
        o.x = (o.x * wi + zj.x * wj) / s;
        o.y = (o.y * wi + zj.y * wj) / s;
        o.z = (o.z * wi + zj.z * wj) / s;
        o.w = (o.w * wi + zj.w * wj) / s;
        if (tid == 0) lout[(long)bb * TL + p] = s;
      } else {
        if (tid == 0) lout[(long)bb * TL + p] = (float)lbat[t];
      }
      *(float4*)(out + ((long)bb * TL + p) * D_ + tid * 4) = o;
      ++p;
    }
  }
}

// ---------------------------------------------------------------------------
// Legacy fallback path (unused for TL=6144, kept for generality)
// ---------------------------------------------------------------------------
__global__ __launch_bounds__(64) void k_pick(
    const double* __restrict__ sims, const int* __restrict__ tlptr,
    int* __restrict__ mrMask, int* __restrict__ keptCnt)
{
  const int win = blockIdx.x * 64 + threadIdx.x;
  if (win >= B_ * NWIN_) return;
  const int w = win % NWIN_;
  const int tl = tlptr[0];
  const int mn = T_ - tl;
  const int base = mn / NWIN_, extra = mn % NWIN_;
  int budget = base + (w < extra ? 1 : 0);
  if (budget > WSZ_ / 2) budget = WSZ_ / 2;
  if (budget < 0) budget = 0;
  double v[WSZ_ - 1];
  int id[WSZ_ - 1];
  for (int e = 0; e < WSZ_ - 1; ++e) {
    v[e] = sims[(long)win * (WSZ_ - 1) + e];
    id[e] = e;
  }
  for (int i = 1; i < WSZ_ - 1; ++i) {
    const double dv = v[i]; const int di = id[i];
    int j = i - 1;
    while (j >= 0 && v[j] < dv) { v[j + 1] = v[j]; id[j + 1] = id[j]; --j; }
    v[j + 1] = dv; id[j + 1] = di;
  }
  bool used[WSZ_];
  for (int i = 0; i < WSZ_; ++i) used[i] = false;
  int mrm = 0, picked = 0;
  for (int ii = 0; ii < WSZ_ - 1; ++ii) {
    const int e = id[ii];
    if (picked < budget && !used[e] && !used[e + 1]) {
      used[e] = used[e + 1] = true;
      mrm |= (1 << (e + 1));
      ++picked;
    }
  }
  mrMask[win] = mrm;
  keptCnt[win] = WSZ_ - picked;
}

__global__ void k_scan_windows(const int* __restrict__ keptCnt,
                               int* __restrict__ outOff)
{
  const int b = threadIdx.x;
  if (b >= B_) return;
  int off = 0;
  for (int w = 0; w < NWIN_; ++w) {
    outOff[b * NWIN_ + w] = off;
    off += keptCnt[b * NWIN_ + w];
  }
}

__global__ __launch_bounds__(256) void k_emit(
    const float* __restrict__ z, const int* __restrict__ lens,
    const int* __restrict__ mrMask, const int* __restrict__ outOff,
    float* __restrict__ out, int TL)
{
  const int bw = blockIdx.x;
  const int b = bw / NWIN_, w = bw % NWIN_;
  const int tid = threadIdx.x;
  const int mrm = mrMask[bw];
  int p = outOff[bw];
  const int t0 = w * WSZ_;
  const float* zb = z + (long)b * T_ * D_;
  const int* lb = lens + b * T_;
  float* lout = out + (long)B_ * TL * D_;
  for (int i = 0; i < WSZ_; ++i) {
    if ((mrm >> i) & 1) continue;
    if (p >= TL) return;
    const int t = t0 + i;
    const bool ab = (i < WSZ_ - 1) && ((mrm >> (i + 1)) & 1);
    float4 o = *(const float4*)(zb + (long)t * D_ + tid * 4);
    if (ab) {
      const float wi = (float)lb[t], wj = (float)lb[t + 1];
      const float s = wi + wj;
      const float4 zj = *(const float4*)(zb + (long)(t + 1) * D_ + tid * 4);
      o.x = (o.x * wi + zj.x * wj) / s;
      o.y = (o.y * wi + zj.y * wj) / s;
      o.z = (o.z * wi + zj.z * wj) / s;
      o.w = (o.w * wi + zj.w * wj) / s;
      if (tid == 0) lout[(long)b * TL + p] = s;
    } else {
      if (tid == 0) lout[(long)b * TL + p] = (float)lb[t];
    }
    *(float4*)(out + ((long)b * TL + p) * D_ + tid * 4) = o;
    ++p;
  }
}

// ---------------------------------------------------------------------------
// K5: starts = exclusive cumsum of lens_new per row. grid: B blocks, 256 thr.
// ---------------------------------------------------------------------------
__global__ __launch_bounds__(256) void k_starts(
    const float* __restrict__ lens_f, float* __restrict__ starts, int TL)
{
  const int b = blockIdx.x;
  const int tid = threadIdx.x;
  const int lane = tid & 63, wv = tid >> 6;
  __shared__ float wsum[4];
  const float* lrow = lens_f + (long)b * TL;
  float* srow = starts + (long)b * TL;
  float carry = 0.0f;

  for (int c0 = 0; c0 < TL; c0 += 256) {
    const int j = c0 + tid;
    const float v = (j < TL) ? lrow[j] : 0.0f;
    float x = v;
#pragma unroll
    for (int d = 1; d < 64; d <<= 1) {
      const float o = __shfl_up(x, d);
      if (lane >= d) x += o;
    }
    if (lane == 63) wsum[wv] = x;
    __syncthreads();
    float pre = 0.0f;
    if (wv > 0) pre += wsum[0];
    if (wv > 1) pre += wsum[1];
    if (wv > 2) pre += wsum[2];
    const float tot = wsum[0] + wsum[1] + wsum[2] + wsum[3];
    if (j < TL) srow[j] = carry + pre + x - v;
    carry += tot;
    __syncthreads();
  }
}

// ---------------------------------------------------------------------------
extern "C" void kernel_launch(void* const* d_in, const int* in_sizes, int n_in,
                              void* d_out, int out_size, void* d_ws, size_t ws_size,
                              hipStream_t stream)
{
  const float* z    = (const float*)d_in[0];
  const int*   lens = (const int*)d_in[1];
  const float* W1   = (const float*)d_in[2];
  const float* W2   = (const float*)d_in[3];
  const int*   tlp  = (const int*)d_in[4];

  float* out = (float*)d_out;
  const int TL = out_size / (B_ * (D_ + 2));   // 6144

  // static budget analysis (host): greedy always reaches budget when base<=5
  const int merges = T_ - TL;
  const int base = merges / NWIN_;
  const int extra = merges % NWIN_;
  const int doEmit = (extra == 0 && base >= 0 && base <= 5) ? 1 : 0;

  // workspace layout
  double* sims = (double*)d_ws;
  char* p = (char*)d_ws + (size_t)B_ * NWIN_ * (WSZ_ - 1) * 8;
  int* mrMask = (int*)p;
  int* kept   = mrMask + B_ * NWIN_;
  int* outOff = kept + B_ * NWIN_;
  short* w1f = (short*)(p + 3 * B_ * NWIN_ * 4 + 64);
  w1f = (short*)(((size_t)w1f + 15) & ~(size_t)15);
  short* w2f = w1f + 2 * PL1_;

  hipLaunchKernelGGL(k_prep,
                     dim3((4 * 32 * 64 * 8 + 4 * 2 * 64 * 8) / 256), dim3(256),
                     0, stream, W1, W2, w1f, w2f);
  hipLaunchKernelGGL(k_fused, dim3((B_ * T_) / 64), dim3(256), 0, stream,
                     z, w1f, w2f, lens, out, sims, TL, base, doEmit);
  if (!doEmit) {
    hipLaunchKernelGGL(k_pick, dim3((B_ * NWIN_ + 63) / 64), dim3(64), 0,
                       stream, sims, tlp, mrMask, kept);
    hipLaunchKernelGGL(k_scan_windows, dim3(1), dim3(64), 0, stream,
                       kept, outOff);
    hipLaunchKernelGGL(k_emit, dim3(B_ * NWIN_), dim3(256), 0, stream,
                       z, lens, mrMask, outOff, out, TL);
  }
  hipLaunchKernelGGL(k_starts, dim3(B_), dim3(256), 0, stream,
                     out + (long)B_ * TL * D_,
                     out + (long)B_ * TL * D_ + (long)B_ * TL, TL);
}

// Round 20
// 186.213 us; speedup vs baseline: 1.1623x; 1.1623x over previous
//
#include <hip/hip_runtime.h>

#define B_ 8
#define T_ 8192
#define D_ 1024
#define GD_ 64
#define WSZ_ 16
#define NWIN_ (T_ / WSZ_)   // 512
#define PL1_ (4 * 32 * 512) // W1F per-split-plane elems
#define PL2_ (4 * 2 * 512)  // W2F per-split-plane elems

typedef __attribute__((ext_vector_type(8))) short short8v;
typedef __attribute__((ext_vector_type(4))) float f32x4;

__device__ __forceinline__ unsigned bf16rne(unsigned u) {
  return (u + 0x7FFFu + ((u >> 16) & 1u)) >> 16;
}
// f32 -> 2 bf16 terms: x = h + m + O(2^-17 x)
__device__ __forceinline__ void split2(float x, short& h, short& m) {
  const unsigned uh = bf16rne(__float_as_uint(x));
  const float fh = __uint_as_float(uh << 16);
  const float r1 = x - fh;
  const unsigned um = bf16rne(__float_as_uint(r1));
  h = (short)uh; m = (short)um;
}

// ---------------------------------------------------------------------------
// K0: split W1/W2 into MFMA-fragment-tiled bf16 planes (2 splits).
// ---------------------------------------------------------------------------
__global__ __launch_bounds__(256) void k_prep(
    const float* __restrict__ W1, const float* __restrict__ W2,
    short* __restrict__ w1f, short* __restrict__ w2f)
{
  const int i = blockIdx.x * 256 + threadIdx.x;
  if (i < 4 * 32 * 64 * 8) {
    const int e = i & 7;
    const int lane = (i >> 3) & 63;
    const int tk = (i >> 9) & 31;
    const int tg = i >> 14;
    const int g = tg * 16 + (lane & 15);
    const int k = tk * 32 + ((lane >> 4) << 3) + e;
    short h, m;
    split2(W1[(long)k * GD_ + g], h, m);
    const int off = ((tg * 32 + tk) << 9) + lane * 8 + e;
    w1f[off] = h;
    w1f[PL1_ + off] = m;
  } else {
    const int j = i - 4 * 32 * 64 * 8;       // < 4096
    const int e = j & 7;
    const int lane = (j >> 3) & 63;
    const int tk = (j >> 9) & 1;
    const int tg = j >> 10;
    const int g = tg * 16 + (lane & 15);
    const int k = tk * 32 + ((lane >> 4) << 3) + e;
    short h, m;
    split2(W2[(long)k * GD_ + g], h, m);
    const int off = ((tg * 2 + tk) << 9) + lane * 8 + e;
    w2f[off] = h;
    w2f[PL2_ + off] = m;
  }
}

// ---------------------------------------------------------------------------
// K1 (fully fused): sims -> per-window greedy pick -> emit z_new/lens_new.
// MFMA 2-split (hh, hm, mh). When doEmit (budget uniform & always-achievable:
// extra==0, base<=5), picks give exactly (16-base) kept rows per window ->
// static output offsets; pick+emit run in-block. Else writes sims to global
// for the legacy k_pick/k_scan/k_emit path.
// ---------------------------------------------------------------------------
__global__ __launch_bounds__(256) void k_fused(
    const float* __restrict__ z, const short* __restrict__ w1f,
    const short* __restrict__ w2f, const int* __restrict__ lensp,
    float* __restrict__ out, double* __restrict__ sims_out,
    int TL, int baseBudget, int doEmit)
{
  __shared__ short Zsp[2][64][72];     // z/H splits; Gf overlays both planes
  __shared__ double den[64];
  __shared__ double simsL[4][WSZ_ - 1];
  __shared__ int mrmL[4];
  float (*Gf)[72] = (float (*)[72]) & Zsp[0][0][0];   // 18432B == Zsp size

  const int tid = threadIdx.x;
  const int lane = tid & 63;
  const int w = tid >> 6;
  const int th = w & 1;
  const int gh = w >> 1;
  const int cl = lane & 15;
  const int ko8 = (lane >> 4) * 8;
  const long bt0 = (long)blockIdx.x * 64;

  const int r = tid >> 2;
  const int kq = tid & 3;
  const float* zbase = z + (bt0 + r) * D_ + kq * 16;

  f32x4 acc[2][2];
#pragma unroll
  for (int a = 0; a < 2; ++a)
#pragma unroll
    for (int b = 0; b < 2; ++b) acc[a][b] = (f32x4){0.f, 0.f, 0.f, 0.f};

  auto stage = [&](const float4 (&pz)[4]) {
    short h[16], m[16];
#pragma unroll
    for (int q = 0; q < 4; ++q) {
      split2(pz[q].x, h[4 * q + 0], m[4 * q + 0]);
      split2(pz[q].y, h[4 * q + 1], m[4 * q + 1]);
      split2(pz[q].z, h[4 * q + 2], m[4 * q + 2]);
      split2(pz[q].w, h[4 * q + 3], m[4 * q + 3]);
    }
    const int co = kq * 16;
    *(short8v*)&Zsp[0][r][co] =
        (short8v){h[0], h[1], h[2], h[3], h[4], h[5], h[6], h[7]};
    *(short8v*)&Zsp[0][r][co + 8] =
        (short8v){h[8], h[9], h[10], h[11], h[12], h[13], h[14], h[15]};
    *(short8v*)&Zsp[1][r][co] =
        (short8v){m[0], m[1], m[2], m[3], m[4], m[5], m[6], m[7]};
    *(short8v*)&Zsp[1][r][co + 8] =
        (short8v){m[8], m[9], m[10], m[11], m[12], m[13], m[14], m[15]};
  };

  auto mfma_chunk = [&](int c) {
#pragma unroll
    for (int ks = 0; ks < 2; ++ks) {
      const int ko = ks * 32 + ko8;
      short8v af[2][2], bf[2][2];
#pragma unroll
      for (int a = 0; a < 2; ++a)
#pragma unroll
        for (int s = 0; s < 2; ++s)
          af[a][s] = *(const short8v*)(
              w1f + s * PL1_ +
              ((((gh * 2 + a) * 32) + (c * 2 + ks)) << 9) + lane * 8);
#pragma unroll
      for (int b = 0; b < 2; ++b)
#pragma unroll
        for (int s = 0; s < 2; ++s)
          bf[b][s] = *(const short8v*)&Zsp[s][th * 32 + b * 16 + cl][ko];
#pragma unroll
      for (int a = 0; a < 2; ++a)
#pragma unroll
        for (int b = 0; b < 2; ++b) {
          f32x4 d = acc[a][b];
          d = __builtin_amdgcn_mfma_f32_16x16x32_bf16(af[a][0], bf[b][0], d, 0, 0, 0);
          d = __builtin_amdgcn_mfma_f32_16x16x32_bf16(af[a][0], bf[b][1], d, 0, 0, 0);
          d = __builtin_amdgcn_mfma_f32_16x16x32_bf16(af[a][1], bf[b][0], d, 0, 0, 0);
          acc[a][b] = d;
        }
    }
  };

  // ================= phase A: H = z @ W1, pipelined =======================
  float4 pzA[4], pzB[4];
#pragma unroll
  for (int q = 0; q < 4; ++q) pzA[q] = *(const float4*)(zbase + 4 * q);

#pragma unroll 1
  for (int c = 0; c < 16; c += 2) {
    if (c) __syncthreads();
    stage(pzA);
    __syncthreads();
#pragma unroll
    for (int q = 0; q < 4; ++q)
      pzB[q] = *(const float4*)(zbase + (c + 1) * 64 + 4 * q);
    mfma_chunk(c);
    __syncthreads();
    stage(pzB);
    __syncthreads();
    if (c + 2 < 16) {
#pragma unroll
      for (int q = 0; q < 4; ++q)
        pzA[q] = *(const float4*)(zbase + (c + 2) * 64 + 4 * q);
    }
    mfma_chunk(c + 1);
  }
  __syncthreads();

  // ---- relu + H splits into Zsp as [tok][gd]
#pragma unroll
  for (int a = 0; a < 2; ++a)
#pragma unroll
    for (int b = 0; b < 2; ++b) {
      const int t = th * 32 + b * 16 + cl;
      const int g0 = gh * 32 + a * 16 + (lane >> 4) * 4;
      short hh[4], hm[4];
#pragma unroll
      for (int e = 0; e < 4; ++e)
        split2(fmaxf(acc[a][b][e], 0.0f), hh[e], hm[e]);
      Zsp[0][t][g0 + 0] = hh[0]; Zsp[0][t][g0 + 1] = hh[1];
      Zsp[0][t][g0 + 2] = hh[2]; Zsp[0][t][g0 + 3] = hh[3];
      Zsp[1][t][g0 + 0] = hm[0]; Zsp[1][t][g0 + 1] = hm[1];
      Zsp[1][t][g0 + 2] = hm[2]; Zsp[1][t][g0 + 3] = hm[3];
    }
  __syncthreads();

  // ================= phase B: G = H @ W2 (K = 64) =========================
#pragma unroll
  for (int a = 0; a < 2; ++a)
#pragma unroll
    for (int b = 0; b < 2; ++b) acc[a][b] = (f32x4){0.f, 0.f, 0.f, 0.f};
#pragma unroll
  for (int ks = 0; ks < 2; ++ks) {
    const int ko = ks * 32 + ko8;
    short8v af[2][2], bf[2][2];
#pragma unroll
    for (int a = 0; a < 2; ++a)
#pragma unroll
      for (int s = 0; s < 2; ++s)
        af[a][s] = *(const short8v*)(
            w2f + s * PL2_ + ((((gh * 2 + a) * 2) + ks) << 9) + lane * 8);
#pragma unroll
    for (int b = 0; b < 2; ++b)
#pragma unroll
      for (int s = 0; s < 2; ++s)
        bf[b][s] = *(const short8v*)&Zsp[s][th * 32 + b * 16 + cl][ko];
#pragma unroll
    for (int a = 0; a < 2; ++a)
#pragma unroll
      for (int b = 0; b < 2; ++b) {
        f32x4 d = acc[a][b];
        d = __builtin_amdgcn_mfma_f32_16x16x32_bf16(af[a][0], bf[b][0], d, 0, 0, 0);
        d = __builtin_amdgcn_mfma_f32_16x16x32_bf16(af[a][0], bf[b][1], d, 0, 0, 0);
        d = __builtin_amdgcn_mfma_f32_16x16x32_bf16(af[a][1], bf[b][0], d, 0, 0, 0);
        acc[a][b] = d;
      }
  }
  __syncthreads();                   // all H-split reads done (overlay!)

  // ---- raw G (f32) -> overlay
#pragma unroll
  for (int a = 0; a < 2; ++a)
#pragma unroll
    for (int b = 0; b < 2; ++b) {
      const int t = th * 32 + b * 16 + cl;
      const int g0 = gh * 32 + a * 16 + (lane >> 4) * 4;
      *(f32x4*)&Gf[t][g0] = acc[a][b];
    }
  __syncthreads();

  // ---- norms (f64)
  if (tid < 64) {
    double ss = 0.0;
#pragma unroll
    for (int q = 0; q < 16; ++q) {
      const float4 v = *(const float4*)&Gf[tid][4 * q];
      ss += (double)v.x * v.x + (double)v.y * v.y +
            (double)v.z * v.z + (double)v.w * v.w;
    }
    den[tid] = sqrt(ss) + 1e-8;
  }
  __syncthreads();

  // ---- sims (f64) -> LDS (and global if fallback path)
  if (tid < 4 * (WSZ_ - 1)) {
    const int ww = tid / (WSZ_ - 1), e = tid % (WSZ_ - 1);
    const int t = ww * WSZ_ + e;
    double s = 0.0;
#pragma unroll
    for (int q = 0; q < 16; ++q) {
      const float4 x = *(const float4*)&Gf[t][4 * q];
      const float4 y = *(const float4*)&Gf[t + 1][4 * q];
      s += (double)x.x * y.x + (double)x.y * y.y +
           (double)x.z * y.z + (double)x.w * y.w;
    }
    const double sv = s / (den[t] * den[t + 1]);
    simsL[ww][e] = sv;
    if (!doEmit)
      sims_out[((long)blockIdx.x * 4 + ww) * (WSZ_ - 1) + e] = sv;
  }
  if (!doEmit) return;
  __syncthreads();

  // ---- per-window pick (exact k_pick algorithm, budget = baseBudget)
  if (tid < 4) {
    double v[WSZ_ - 1];
    int id[WSZ_ - 1];
    for (int e = 0; e < WSZ_ - 1; ++e) { v[e] = simsL[tid][e]; id[e] = e; }
    for (int i = 1; i < WSZ_ - 1; ++i) {
      const double dv = v[i]; const int di = id[i];
      int j = i - 1;
      while (j >= 0 && v[j] < dv) { v[j + 1] = v[j]; id[j + 1] = id[j]; --j; }
      v[j + 1] = dv; id[j + 1] = di;
    }
    bool used[WSZ_];
    for (int i = 0; i < WSZ_; ++i) used[i] = false;
    int mrm = 0, picked = 0;
    for (int ii = 0; ii < WSZ_ - 1; ++ii) {
      const int e = id[ii];
      if (picked < baseBudget && !used[e] && !used[e + 1]) {
        used[e] = used[e + 1] = true;
        mrm |= (1 << (e + 1));
        ++picked;
      }
    }
    mrmL[tid] = mrm;
  }
  __syncthreads();

  // ---- emit: static offsets (keptW per window), coalesced float4 rows
  const int keptW = WSZ_ - baseBudget;
  const int bb = (int)(bt0 / T_);
  const int tb = (int)(bt0 % T_);
  const int wb = tb / WSZ_;
  const float* zbat = z + (long)bb * T_ * D_;
  const int* lbat = lensp + bb * T_;
  float* lout = out + (long)B_ * TL * D_;

#pragma unroll 1
  for (int ww2 = 0; ww2 < 4; ++ww2) {
    const int mrm = mrmL[ww2];
    int p = keptW * (wb + ww2);
    const int t0 = tb + ww2 * WSZ_;
#pragma unroll 1
    for (int i = 0; i < WSZ_; ++i) {
      if ((mrm >> i) & 1) continue;
      const int t = t0 + i;
      const bool ab = (i < WSZ_ - 1) && ((mrm >> (i + 1)) & 1);
      float4 o = *(const float4*)(zbat + (long)t * D_ + tid * 4);
      if (ab) {
        const float wi = (float)lbat[t], wj = (float)lbat[t + 1];
        const float s = wi + wj;
        const float4 zj = *(const float4*)(zbat + (long)(t + 1) * D_ + tid * 4);
        o.x = (o.x * wi + zj.x * wj) / s;
        o.y = (o.y * wi + zj.y * wj) / s;
        o.z = (o.z * wi + zj.z * wj) / s;
        o.w = (o.w * wi + zj.w * wj) / s;
        if (tid == 0) lout[(long)bb * TL + p] = s;
      } else {
        if (tid == 0) lout[(long)bb * TL + p] = (float)lbat[t];
      }
      *(float4*)(out + ((long)bb * TL + p) * D_ + tid * 4) = o;
      ++p;
    }
  }
}

// ---------------------------------------------------------------------------
// Legacy fallback path (unused for TL=6144, kept for generality)
// ---------------------------------------------------------------------------
__global__ __launch_bounds__(64) void k_pick(
    const double* __restrict__ sims, const int* __restrict__ tlptr,
    int* __restrict__ mrMask, int* __restrict__ keptCnt)
{
  const int win = blockIdx.x * 64 + threadIdx.x;
  if (win >= B_ * NWIN_) return;
  const int w = win % NWIN_;
  const int tl = tlptr[0];
  const int mn = T_ - tl;
  const int base = mn / NWIN_, extra = mn % NWIN_;
  int budget = base + (w < extra ? 1 : 0);
  if (budget > WSZ_ / 2) budget = WSZ_ / 2;
  if (budget < 0) budget = 0;
  double v[WSZ_ - 1];
  int id[WSZ_ - 1];
  for (int e = 0; e < WSZ_ - 1; ++e) {
    v[e] = sims[(long)win * (WSZ_ - 1) + e];
    id[e] = e;
  }
  for (int i = 1; i < WSZ_ - 1; ++i) {
    const double dv = v[i]; const int di = id[i];
    int j = i - 1;
    while (j >= 0 && v[j] < dv) { v[j + 1] = v[j]; id[j + 1] = id[j]; --j; }
    v[j + 1] = dv; id[j + 1] = di;
  }
  bool used[WSZ_];
  for (int i = 0; i < WSZ_; ++i) used[i] = false;
  int mrm = 0, picked = 0;
  for (int ii = 0; ii < WSZ_ - 1; ++ii) {
    const int e = id[ii];
    if (picked < budget && !used[e] && !used[e + 1]) {
      used[e] = used[e + 1] = true;
      mrm |= (1 << (e + 1));
      ++picked;
    }
  }
  mrMask[win] = mrm;
  keptCnt[win] = WSZ_ - picked;
}

__global__ void k_scan_windows(const int* __restrict__ keptCnt,
                               int* __restrict__ outOff)
{
  const int b = threadIdx.x;
  if (b >= B_) return;
  int off = 0;
  for (int w = 0; w < NWIN_; ++w) {
    outOff[b * NWIN_ + w] = off;
    off += keptCnt[b * NWIN_ + w];
  }
}

__global__ __launch_bounds__(256) void k_emit(
    const float* __restrict__ z, const int* __restrict__ lens,
    const int* __restrict__ mrMask, const int* __restrict__ outOff,
    float* __restrict__ out, int TL)
{
  const int bw = blockIdx.x;
  const int b = bw / NWIN_, w = bw % NWIN_;
  const int tid = threadIdx.x;
  const int mrm = mrMask[bw];
  int p = outOff[bw];
  const int t0 = w * WSZ_;
  const float* zb = z + (long)b * T_ * D_;
  const int* lb = lens + b * T_;
  float* lout = out + (long)B_ * TL * D_;
  for (int i = 0; i < WSZ_; ++i) {
    if ((mrm >> i) & 1) continue;
    if (p >= TL) return;
    const int t = t0 + i;
    const bool ab = (i < WSZ_ - 1) && ((mrm >> (i + 1)) & 1);
    float4 o = *(const float4*)(zb + (long)t * D_ + tid * 4);
    if (ab) {
      const float wi = (float)lb[t], wj = (float)lb[t + 1];
      const float s = wi + wj;
      const float4 zj = *(const float4*)(zb + (long)(t + 1) * D_ + tid * 4);
      o.x = (o.x * wi + zj.x * wj) / s;
      o.y = (o.y * wi + zj.y * wj) / s;
      o.z = (o.z * wi + zj.z * wj) / s;
      o.w = (o.w * wi + zj.w * wj) / s;
      if (tid == 0) lout[(long)b * TL + p] = s;
    } else {
      if (tid == 0) lout[(long)b * TL + p] = (float)lb[t];
    }
    *(float4*)(out + ((long)b * TL + p) * D_ + tid * 4) = o;
    ++p;
  }
}

// ---------------------------------------------------------------------------
// K5: starts = exclusive cumsum of lens_new per row. grid: B blocks, 256 thr.
// ---------------------------------------------------------------------------
__global__ __launch_bounds__(256) void k_starts(
    const float* __restrict__ lens_f, float* __restrict__ starts, int TL)
{
  const int b = blockIdx.x;
  const int tid = threadIdx.x;
  const int lane = tid & 63, wv = tid >> 6;
  __shared__ float wsum[4];
  const float* lrow = lens_f + (long)b * TL;
  float* srow = starts + (long)b * TL;
  float carry = 0.0f;

  for (int c0 = 0; c0 < TL; c0 += 256) {
    const int j = c0 + tid;
    const float v = (j < TL) ? lrow[j] : 0.0f;
    float x = v;
#pragma unroll
    for (int d = 1; d < 64; d <<= 1) {
      const float o = __shfl_up(x, d);
      if (lane >= d) x += o;
    }
    if (lane == 63) wsum[wv] = x;
    __syncthreads();
    float pre = 0.0f;
    if (wv > 0) pre += wsum[0];
    if (wv > 1) pre += wsum[1];
    if (wv > 2) pre += wsum[2];
    const float tot = wsum[0] + wsum[1] + wsum[2] + wsum[3];
    if (j < TL) srow[j] = carry + pre + x - v;
    carry += tot;
    __syncthreads();
  }
}

// ---------------------------------------------------------------------------
extern "C" void kernel_launch(void* const* d_in, const int* in_sizes, int n_in,
                              void* d_out, int out_size, void* d_ws, size_t ws_size,
                              hipStream_t stream)
{
  const float* z    = (const float*)d_in[0];
  const int*   lens = (const int*)d_in[1];
  const float* W1   = (const float*)d_in[2];
  const float* W2   = (const float*)d_in[3];
  const int*   tlp  = (const int*)d_in[4];

  float* out = (float*)d_out;
  const int TL = out_size / (B_ * (D_ + 2));   // 6144

  // static budget analysis (host): picks always reach budget when base<=5
  const int merges = T_ - TL;
  const int base = merges / NWIN_;
  const int extra = merges % NWIN_;
  const int doEmit = (extra == 0 && base >= 0 && base <= 5) ? 1 : 0;

  // workspace layout
  double* sims = (double*)d_ws;
  char* p = (char*)d_ws + (size_t)B_ * NWIN_ * (WSZ_ - 1) * 8;
  int* mrMask = (int*)p;
  int* kept   = mrMask + B_ * NWIN_;
  int* outOff = kept + B_ * NWIN_;
  short* w1f = (short*)(p + 3 * B_ * NWIN_ * 4 + 64);
  w1f = (short*)(((size_t)w1f + 15) & ~(size_t)15);
  short* w2f = w1f + 2 * PL1_;

  hipLaunchKernelGGL(k_prep,
                     dim3((4 * 32 * 64 * 8 + 4 * 2 * 64 * 8) / 256), dim3(256),
                     0, stream, W1, W2, w1f, w2f);
  hipLaunchKernelGGL(k_fused, dim3((B_ * T_) / 64), dim3(256), 0, stream,
                     z, w1f, w2f, lens, out, sims, TL, base, doEmit);
  if (!doEmit) {
    hipLaunchKernelGGL(k_pick, dim3((B_ * NWIN_ + 63) / 64), dim3(64), 0,
                       stream, sims, tlp, mrMask, kept);
    hipLaunchKernelGGL(k_scan_windows, dim3(1), dim3(64), 0, stream,
                       kept, outOff);
    hipLaunchKernelGGL(k_emit, dim3(B_ * NWIN_), dim3(256), 0, stream,
                       z, lens, mrMask, outOff, out, TL);
  }
  hipLaunchKernelGGL(k_starts, dim3(B_), dim3(256), 0, stream,
                     out + (long)B_ * TL * D_,
                     out + (long)B_ * TL * D_ + (long)B_ * TL, TL);
}